// Round 1
// baseline (397.140 us; speedup 1.0000x reference)
//
#include <hip/hip_runtime.h>

typedef unsigned short u16;
typedef __bf16 bf16x8 __attribute__((ext_vector_type(8)));
typedef float f32x4 __attribute__((ext_vector_type(4)));

// fp32 -> bf16 with round-to-nearest-even (values are finite & small; no NaN path needed)
__device__ __forceinline__ u16 f2bf(float f) {
  unsigned int u = __float_as_uint(f);
  unsigned int r = (u + 0x7fffu + ((u >> 16) & 1u)) >> 16;
  return (u16)r;
}

// ---------------------------------------------------------------------------
// Kernel 1: scaled permutation counts C[i][g][j] = count/12, and concat bias
// ---------------------------------------------------------------------------
__global__ void k_prep(const int* p0, const int* p1, const int* p2, const int* p3,
                       const int* p4, const int* p5, const int* p6,
                       const float* b0, const float* b1, const float* b2, const float* b3,
                       const float* b4, const float* b5, const float* b6,
                       float* __restrict__ Ccnt, float* __restrict__ bcat) {
  const int tid = threadIdx.x;
  const int* ps[7] = {p0, p1, p2, p3, p4, p5, p6};
  const float* bs[7] = {b0, b1, b2, b3, b4, b5, b6};
  for (int cell = tid; cell < 7 * 64; cell += 256) {
    int i = cell >> 6;          // scale index, scale = 8-i
    int rem = cell & 63;
    int g = rem >> 3;           // source group 0..7
    int j = rem & 7;            // slot within permutation
    int scale = 8 - i;
    float v = 0.f;
    if (j < scale) {
      const int* p = ps[i];
      int cnt = 0;
      for (int s = 0; s < 12; ++s) cnt += (p[s * scale + j] == g) ? 1 : 0;
      v = (float)cnt * (1.0f / 12.0f);
    }
    Ccnt[cell] = v;
  }
  for (int idx = tid; idx < 7168; idx += 256) {
    int i = idx >> 10;
    int d = idx & 1023;
    bcat[idx] = bs[i][d];
  }
}

// ---------------------------------------------------------------------------
// Kernel 2: cast input fp32 (2048x4096) -> bf16
// ---------------------------------------------------------------------------
__global__ void k_cvt(const float* __restrict__ x, u16* __restrict__ Ab) {
  int idx = blockIdx.x * 256 + threadIdx.x;   // 2,097,152 float4s
  const float4 v = reinterpret_cast<const float4*>(x)[idx];
  ushort4 o;
  o.x = f2bf(v.x); o.y = f2bf(v.y); o.z = f2bf(v.z); o.w = f2bf(v.w);
  reinterpret_cast<ushort4*>(Ab)[idx] = o;
}

// ---------------------------------------------------------------------------
// Kernel 3: build Weff (7168 rows x 4096 cols) in bf16, row-major
//   Weff[i*1024+d][g*512+f] = sum_j C[i][g][j] * W_i[d, j*512+f]
// One block per output row; each thread handles 16 contiguous columns.
// ---------------------------------------------------------------------------
__global__ void k_weff(const float* W0, const float* W1, const float* W2, const float* W3,
                       const float* W4, const float* W5, const float* W6,
                       const float* __restrict__ Ccnt, u16* __restrict__ Wb) {
  const int n = blockIdx.x;     // 0..7167
  const int i = n >> 10;
  const int d = n & 1023;
  const int scale = 8 - i;
  const int t = threadIdx.x;
  const int g = t >> 5;              // column group (t*16)>>9
  const int f0 = (t & 31) * 16;      // feature offset within group
  const float* Wi = (i == 0) ? W0 : (i == 1) ? W1 : (i == 2) ? W2 :
                    (i == 3) ? W3 : (i == 4) ? W4 : (i == 5) ? W5 : W6;
  const float* wrow = Wi + (size_t)d * (scale * 512);
  float acc[16];
#pragma unroll
  for (int k = 0; k < 16; ++k) acc[k] = 0.f;
  for (int j = 0; j < scale; ++j) {
    float cf = Ccnt[i * 64 + g * 8 + j];
    if (cf != 0.f) {
      const float4* src = reinterpret_cast<const float4*>(wrow + j * 512 + f0);
#pragma unroll
      for (int v = 0; v < 4; ++v) {
        float4 w = src[v];
        acc[v * 4 + 0] += cf * w.x;
        acc[v * 4 + 1] += cf * w.y;
        acc[v * 4 + 2] += cf * w.z;
        acc[v * 4 + 3] += cf * w.w;
      }
    }
  }
  unsigned int packed[8];
#pragma unroll
  for (int k = 0; k < 8; ++k)
    packed[k] = (unsigned int)f2bf(acc[2 * k]) | ((unsigned int)f2bf(acc[2 * k + 1]) << 16);
  uint4* dst = reinterpret_cast<uint4*>(Wb + (size_t)n * 4096 + t * 16);
  dst[0] = make_uint4(packed[0], packed[1], packed[2], packed[3]);
  dst[1] = make_uint4(packed[4], packed[5], packed[6], packed[7]);
}

// ---------------------------------------------------------------------------
// Kernel 4: bf16 MFMA GEMM  out(2048x7168) = A(2048x4096) @ Wb(7168x4096)^T + bias
// 128x128 block tile, BK=32, 4 waves (2x2), each wave 64x64 = 4x4 frags of
// 16x16x32. Staging via global_load_lds width 16 (m97 structure).
// ---------------------------------------------------------------------------
__device__ __forceinline__ void gl_lds16(const u16* g, u16* l) {
  __builtin_amdgcn_global_load_lds(
      (const __attribute__((address_space(1))) void*)g,
      (__attribute__((address_space(3))) void*)l, 16, 0, 0);
}

__global__ __launch_bounds__(256) void k_gemm(const u16* __restrict__ Ab,
                                              const u16* __restrict__ Wb,
                                              const float* __restrict__ bcat,
                                              float* __restrict__ out) {
  __shared__ u16 sA[128 * 32];
  __shared__ u16 sB[128 * 32];
  const int tid = threadIdx.x;
  const int lane = tid & 63;
  const int wave = tid >> 6;
  const int quad = lane >> 4;
  const int l15 = lane & 15;
  const int m0 = blockIdx.y * 128;
  const int n0 = blockIdx.x * 128;
  const int waveM = (wave >> 1) * 64;
  const int waveN = (wave & 1) * 64;

  // Staging: tile row = 32 bf16 = 64B = 4 chunks of 16B. 512 chunks per tile,
  // 256 threads -> 2 chunks/thread. LDS dest is (implicitly) base + lane*16.
  const int rowq = tid >> 2;   // 0..63
  const int chunk = tid & 3;
  const u16* pA0 = Ab + (size_t)(m0 + rowq) * 4096 + chunk * 8;
  const u16* pA1 = pA0 + (size_t)64 * 4096;
  const u16* pB0 = Wb + (size_t)(n0 + rowq) * 4096 + chunk * 8;
  const u16* pB1 = pB0 + (size_t)64 * 4096;
  u16* lA0 = sA + tid * 8;
  u16* lA1 = lA0 + 2048;
  u16* lB0 = sB + tid * 8;
  u16* lB1 = lB0 + 2048;

  f32x4 acc[4][4];
#pragma unroll
  for (int r = 0; r < 4; ++r)
#pragma unroll
    for (int c = 0; c < 4; ++c) {
      f32x4 z = {0.f, 0.f, 0.f, 0.f};
      acc[r][c] = z;
    }

  for (int kt = 0; kt < 128; ++kt) {
    gl_lds16(pA0, lA0);
    gl_lds16(pA1, lA1);
    gl_lds16(pB0, lB0);
    gl_lds16(pB1, lB1);
    pA0 += 32; pA1 += 32; pB0 += 32; pB1 += 32;
    __syncthreads();   // drains vmcnt -> LDS data visible

    bf16x8 av[4], bv[4];
#pragma unroll
    for (int r = 0; r < 4; ++r)
      av[r] = *reinterpret_cast<const bf16x8*>(sA + (waveM + r * 16 + l15) * 32 + quad * 8);
#pragma unroll
    for (int c = 0; c < 4; ++c)
      bv[c] = *reinterpret_cast<const bf16x8*>(sB + (waveN + c * 16 + l15) * 32 + quad * 8);
#pragma unroll
    for (int r = 0; r < 4; ++r)
#pragma unroll
      for (int c = 0; c < 4; ++c)
        acc[r][c] = __builtin_amdgcn_mfma_f32_16x16x32_bf16(av[r], bv[c], acc[r][c], 0, 0, 0);
    __syncthreads();   // protect LDS from next-iter staging
  }

  // Epilogue: C/D layout row = quad*4 + reg, col = lane&15
#pragma unroll
  for (int c = 0; c < 4; ++c) {
    const int n = n0 + waveN + c * 16 + l15;
    const float bias = bcat[n];
#pragma unroll
    for (int r = 0; r < 4; ++r) {
      const int mbase = m0 + waveM + r * 16 + quad * 4;
#pragma unroll
      for (int reg = 0; reg < 4; ++reg)
        out[(size_t)(mbase + reg) * 7168 + n] = acc[r][c][reg] + bias;
    }
  }
}

// ---------------------------------------------------------------------------
extern "C" void kernel_launch(void* const* d_in, const int* in_sizes, int n_in,
                              void* d_out, int out_size, void* d_ws, size_t ws_size,
                              hipStream_t stream) {
  const float* input = (const float*)d_in[0];
  const int* perms[7];
  const float* W[7];
  const float* bias[7];
  for (int i = 0; i < 7; ++i) {
    perms[i] = (const int*)d_in[1 + 3 * i];
    W[i]     = (const float*)d_in[2 + 3 * i];
    bias[i]  = (const float*)d_in[3 + 3 * i];
  }
  char* ws = (char*)d_ws;
  float* Ccnt = (float*)ws;                          // 448 floats
  float* bcat = (float*)(ws + 4096);                 // 7168 floats
  u16* Ab = (u16*)(ws + 65536);                      // 2048*4096 bf16 = 16 MiB
  u16* Wb = (u16*)(ws + 65536 + 16777216);           // 7168*4096 bf16 = 56 MiB

  k_prep<<<1, 256, 0, stream>>>(perms[0], perms[1], perms[2], perms[3], perms[4],
                                perms[5], perms[6],
                                bias[0], bias[1], bias[2], bias[3], bias[4],
                                bias[5], bias[6], Ccnt, bcat);
  k_cvt<<<8192, 256, 0, stream>>>(input, Ab);
  k_weff<<<7168, 256, 0, stream>>>(W[0], W[1], W[2], W[3], W[4], W[5], W[6], Ccnt, Wb);
  dim3 grid(56, 16);
  k_gemm<<<grid, 256, 0, stream>>>(Ab, Wb, bcat, (float*)d_out);
}

// Round 2
// 349.926 us; speedup vs baseline: 1.1349x; 1.1349x over previous
//
#include <hip/hip_runtime.h>

typedef unsigned short u16;
typedef __bf16 bf16x8 __attribute__((ext_vector_type(8)));
typedef float f32x4 __attribute__((ext_vector_type(4)));

// fp32 -> bf16 round-to-nearest-even (finite, small values; no NaN path)
__device__ __forceinline__ u16 f2bf(float f) {
  unsigned int u = __float_as_uint(f);
  unsigned int r = (u + 0x7fffu + ((u >> 16) & 1u)) >> 16;
  return (u16)r;
}

// ---------------------------------------------------------------------------
// Kernel 1: scaled permutation counts C[i][g][j] = count/12, and concat bias
// ---------------------------------------------------------------------------
__global__ void k_prep(const int* p0, const int* p1, const int* p2, const int* p3,
                       const int* p4, const int* p5, const int* p6,
                       const float* b0, const float* b1, const float* b2, const float* b3,
                       const float* b4, const float* b5, const float* b6,
                       float* __restrict__ Ccnt, float* __restrict__ bcat) {
  const int tid = threadIdx.x;
  const int* ps[7] = {p0, p1, p2, p3, p4, p5, p6};
  const float* bs[7] = {b0, b1, b2, b3, b4, b5, b6};
  for (int cell = tid; cell < 7 * 64; cell += 256) {
    int i = cell >> 6;          // scale index, scale = 8-i
    int rem = cell & 63;
    int g = rem >> 3;           // source group 0..7
    int j = rem & 7;            // slot within permutation
    int scale = 8 - i;
    float v = 0.f;
    if (j < scale) {
      const int* p = ps[i];
      int cnt = 0;
      for (int s = 0; s < 12; ++s) cnt += (p[s * scale + j] == g) ? 1 : 0;
      v = (float)cnt * (1.0f / 12.0f);
    }
    Ccnt[cell] = v;
  }
  for (int idx = tid; idx < 7168; idx += 256) {
    int i = idx >> 10;
    int d = idx & 1023;
    bcat[idx] = bs[i][d];
  }
}

// ---------------------------------------------------------------------------
// Kernel 2: cast input fp32 (2048x4096) -> bf16
// ---------------------------------------------------------------------------
__global__ void k_cvt(const float* __restrict__ x, u16* __restrict__ Ab) {
  int idx = blockIdx.x * 256 + threadIdx.x;   // 2,097,152 float4s
  const float4 v = reinterpret_cast<const float4*>(x)[idx];
  ushort4 o;
  o.x = f2bf(v.x); o.y = f2bf(v.y); o.z = f2bf(v.z); o.w = f2bf(v.w);
  reinterpret_cast<ushort4*>(Ab)[idx] = o;
}

// ---------------------------------------------------------------------------
// Kernel 3: build Weff (7168 rows x 4096 cols) in bf16, row-major.
// Coalesced: float4-index o_v = t + v*256 in the output row; since
// 256 % 128 == 0, all 4 v share the same source float4 w4[j*128 + (t&127)]
// (only the group g = (t>>7) + 2v and hence the Ccnt coefficient differs).
// ---------------------------------------------------------------------------
__global__ void k_weff(const float* W0, const float* W1, const float* W2, const float* W3,
                       const float* W4, const float* W5, const float* W6,
                       const float* __restrict__ Ccnt, u16* __restrict__ Wb) {
  __shared__ float sc[64];
  const int n = blockIdx.x;     // 0..7167
  const int i = n >> 10;
  const int d = n & 1023;
  const int scale = 8 - i;
  const int t = threadIdx.x;
  if (t < 64) sc[t] = Ccnt[i * 64 + t];
  __syncthreads();
  const float* Wi = (i == 0) ? W0 : (i == 1) ? W1 : (i == 2) ? W2 :
                    (i == 3) ? W3 : (i == 4) ? W4 : (i == 5) ? W5 : W6;
  const float4* w4 = reinterpret_cast<const float4*>(Wi + (size_t)d * (scale * 512));
  const int f4 = t & 127;
  const int ghi = t >> 7;       // 0 or 1
  float4 acc[4];
#pragma unroll
  for (int v = 0; v < 4; ++v) acc[v] = make_float4(0.f, 0.f, 0.f, 0.f);
  for (int j = 0; j < scale; ++j) {
    const float4 wv = w4[j * 128 + f4];
#pragma unroll
    for (int v = 0; v < 4; ++v) {
      const float cf = sc[(ghi + 2 * v) * 8 + j];
      acc[v].x += cf * wv.x;
      acc[v].y += cf * wv.y;
      acc[v].z += cf * wv.z;
      acc[v].w += cf * wv.w;
    }
  }
  u16* orow = Wb + (size_t)n * 4096;
#pragma unroll
  for (int v = 0; v < 4; ++v) {
    ushort4 o;
    o.x = f2bf(acc[v].x); o.y = f2bf(acc[v].y);
    o.z = f2bf(acc[v].z); o.w = f2bf(acc[v].w);
    *reinterpret_cast<ushort4*>(orow + (size_t)(t + v * 256) * 4) = o;
  }
}

// ---------------------------------------------------------------------------
// Kernel 4: bf16 MFMA GEMM  out(2048x7168) = A(2048x4096) @ Wb(7168x4096)^T + bias
// 128x128 block tile, BK=64 (32 KB LDS), 4 waves (2x2), each wave 64x64 =
// 4x4 frags of 16x16x32, 2 k-steps per iteration. Staging via global_load_lds
// width 16. LDS rows are 128 B (one bank period); chunk c of row r is stored
// at slot (c + r) & 7 -> read groups cycle all 8 bank-groups (conflict-free).
// ---------------------------------------------------------------------------
__device__ __forceinline__ void gl_lds16(const u16* g, u16* l) {
  __builtin_amdgcn_global_load_lds(
      (const __attribute__((address_space(1))) void*)g,
      (__attribute__((address_space(3))) void*)l, 16, 0, 0);
}

__global__ __launch_bounds__(256) void k_gemm(const u16* __restrict__ Ab,
                                              const u16* __restrict__ Wb,
                                              const float* __restrict__ bcat,
                                              float* __restrict__ out) {
  __shared__ u16 sA[128 * 64];
  __shared__ u16 sB[128 * 64];
  const int tid = threadIdx.x;
  const int lane = tid & 63;
  const int wave = tid >> 6;
  const int quad = lane >> 4;
  const int l15 = lane & 15;
  const int m0 = blockIdx.y * 128;
  const int n0 = blockIdx.x * 128;
  const int waveM = (wave >> 1) * 64;
  const int waveN = (wave & 1) * 64;

  // Staging: tile = 128 rows x 128 B = 1024 chunks of 16 B; 4 chunks/thread.
  // chunk cidx = tid + j*256: row = cidx>>3, slot = cidx&7. Since 256%8==0,
  // slot and the global chunk gch = (slot - row)&7 mod out to gch_j = gch_0
  // (32j rows offset, 32%8==0) -> pA[j] = pA[0] + j*32*4096.
  {
  }
  const int srow = tid >> 3;          // 0..31 (row within first j-slab)
  const int sslot = tid & 7;
  const int gch = (sslot - srow) & 7; // global 16B-chunk to fetch
  const u16* pA0 = Ab + (size_t)(m0 + srow) * 4096 + gch * 8;
  const u16* pB0 = Wb + (size_t)(n0 + srow) * 4096 + gch * 8;
  u16* lA0 = sA + tid * 8;
  u16* lB0 = sB + tid * 8;

  // Precomputed LDS read offsets (u16 units): row*64 + slot(c,row)*8,
  // c = t*4 + quad, slot = (c + row) & 7.
  int offA[2][4], offB[2][4];
#pragma unroll
  for (int t = 0; t < 2; ++t) {
#pragma unroll
    for (int r = 0; r < 4; ++r) {
      int rowA = waveM + r * 16 + l15;
      offA[t][r] = rowA * 64 + (((t * 4 + quad) + rowA) & 7) * 8;
      int rowB = waveN + r * 16 + l15;
      offB[t][r] = rowB * 64 + (((t * 4 + quad) + rowB) & 7) * 8;
    }
  }

  f32x4 acc[4][4];
#pragma unroll
  for (int r = 0; r < 4; ++r)
#pragma unroll
    for (int c = 0; c < 4; ++c) {
      f32x4 z = {0.f, 0.f, 0.f, 0.f};
      acc[r][c] = z;
    }

  for (int kt = 0; kt < 64; ++kt) {
    const size_t ko = (size_t)kt * 64;
#pragma unroll
    for (int j = 0; j < 4; ++j) {
      gl_lds16(pA0 + (size_t)j * 32 * 4096 + ko, lA0 + j * 2048);
      gl_lds16(pB0 + (size_t)j * 32 * 4096 + ko, lB0 + j * 2048);
    }
    __syncthreads();   // drains vmcnt -> LDS data visible

#pragma unroll
    for (int t = 0; t < 2; ++t) {
      bf16x8 av[4], bv[4];
#pragma unroll
      for (int r = 0; r < 4; ++r) av[r] = *reinterpret_cast<const bf16x8*>(sA + offA[t][r]);
#pragma unroll
      for (int c = 0; c < 4; ++c) bv[c] = *reinterpret_cast<const bf16x8*>(sB + offB[t][c]);
#pragma unroll
      for (int r = 0; r < 4; ++r)
#pragma unroll
        for (int c = 0; c < 4; ++c)
          acc[r][c] = __builtin_amdgcn_mfma_f32_16x16x32_bf16(av[r], bv[c], acc[r][c], 0, 0, 0);
    }
    __syncthreads();   // protect LDS from next-iter staging
  }

  // Epilogue: C/D layout row = quad*4 + reg, col = lane&15
#pragma unroll
  for (int c = 0; c < 4; ++c) {
    const int n = n0 + waveN + c * 16 + l15;
    const float bias = bcat[n];
#pragma unroll
    for (int r = 0; r < 4; ++r) {
      const int mbase = m0 + waveM + r * 16 + quad * 4;
#pragma unroll
      for (int reg = 0; reg < 4; ++reg)
        out[(size_t)(mbase + reg) * 7168 + n] = acc[r][c][reg] + bias;
    }
  }
}

// ---------------------------------------------------------------------------
extern "C" void kernel_launch(void* const* d_in, const int* in_sizes, int n_in,
                              void* d_out, int out_size, void* d_ws, size_t ws_size,
                              hipStream_t stream) {
  const float* input = (const float*)d_in[0];
  const int* perms[7];
  const float* W[7];
  const float* bias[7];
  for (int i = 0; i < 7; ++i) {
    perms[i] = (const int*)d_in[1 + 3 * i];
    W[i]     = (const float*)d_in[2 + 3 * i];
    bias[i]  = (const float*)d_in[3 + 3 * i];
  }
  char* ws = (char*)d_ws;
  float* Ccnt = (float*)ws;                          // 448 floats
  float* bcat = (float*)(ws + 4096);                 // 7168 floats
  u16* Ab = (u16*)(ws + 65536);                      // 2048*4096 bf16 = 16 MiB
  u16* Wb = (u16*)(ws + 65536 + 16777216);           // 7168*4096 bf16 = 56 MiB

  k_prep<<<1, 256, 0, stream>>>(perms[0], perms[1], perms[2], perms[3], perms[4],
                                perms[5], perms[6],
                                bias[0], bias[1], bias[2], bias[3], bias[4],
                                bias[5], bias[6], Ccnt, bcat);
  k_cvt<<<8192, 256, 0, stream>>>(input, Ab);
  k_weff<<<7168, 256, 0, stream>>>(W[0], W[1], W[2], W[3], W[4], W[5], W[6], Ccnt, Wb);
  dim3 grid(56, 16);
  k_gemm<<<grid, 256, 0, stream>>>(Ab, Wb, bcat, (float*)d_out);
}

// Round 3
// 321.485 us; speedup vs baseline: 1.2353x; 1.0885x over previous
//
#include <hip/hip_runtime.h>

typedef unsigned short u16;
typedef __bf16 bf16x8 __attribute__((ext_vector_type(8)));
typedef float f32x4 __attribute__((ext_vector_type(4)));

// fp32 -> bf16 round-to-nearest-even (finite, small values; no NaN path)
__device__ __forceinline__ u16 f2bf(float f) {
  unsigned int u = __float_as_uint(f);
  return (u16)((u + 0x7fffu + ((u >> 16) & 1u)) >> 16);
}

// cumK(i) = sum_{i'<i} (8-i')*512 = 256*i*(17-i); K_i = (8-i)*512
__device__ __forceinline__ int cumK(int i) { return 256 * i * (17 - i); }

// ---------------------------------------------------------------------------
// Kernel 1: xbar build. For each batch row b:
//   Xb[b, cumK(i) + j*512 + f] = bf16( sum_g C_i[g,j] * x[b, g*512 + f] )
// C_i[g,j] = (#s: perms_i[s,j]==g)/12, computed per-block into LDS (cheap,
// perms are tiny and L2-resident). One block per b; lane u=t&63 owns 8
// consecutive f (16B stores); wave v=t>>6 walks slots s = v,v+4,...
// ---------------------------------------------------------------------------
__global__ __launch_bounds__(256) void k_xbar(
    const float* __restrict__ x,
    const int* p0, const int* p1, const int* p2, const int* p3,
    const int* p4, const int* p5, const int* p6,
    u16* __restrict__ Xb) {
  __shared__ float sc[448];
  const int b = blockIdx.x;
  const int t = threadIdx.x;
  const int* ps[7] = {p0, p1, p2, p3, p4, p5, p6};
  for (int cell = t; cell < 448; cell += 256) {
    int i = cell >> 6, rem = cell & 63, g = rem >> 3, j = rem & 7;
    int scale = 8 - i;
    float v = 0.f;
    if (j < scale) {
      const int* p = ps[i];
      int cnt = 0;
      for (int s = 0; s < 12; ++s) cnt += (p[s * scale + j] == g) ? 1 : 0;
      v = (float)cnt * (1.0f / 12.0f);
    }
    sc[cell] = v;
  }
  __syncthreads();
  const int u = t & 63;
  const int wv = t >> 6;
  const float4* xrow = reinterpret_cast<const float4*>(x + (size_t)b * 4096);
  float4 xr0[8], xr1[8];
#pragma unroll
  for (int g = 0; g < 8; ++g) {
    xr0[g] = xrow[g * 128 + u * 2];
    xr1[g] = xrow[g * 128 + u * 2 + 1];
  }
  u16* orow = Xb + (size_t)b * 17920;
  for (int s = wv; s < 35; s += 4) {
    int i = 0, rem = s;                 // wave-uniform decode of (i, j)
    while (rem >= 8 - i) { rem -= 8 - i; ++i; }
    const int j = rem;
    float4 A0 = make_float4(0.f, 0.f, 0.f, 0.f);
    float4 A1 = make_float4(0.f, 0.f, 0.f, 0.f);
#pragma unroll
    for (int g = 0; g < 8; ++g) {
      const float c = sc[i * 64 + g * 8 + j];
      A0.x += c * xr0[g].x; A0.y += c * xr0[g].y;
      A0.z += c * xr0[g].z; A0.w += c * xr0[g].w;
      A1.x += c * xr1[g].x; A1.y += c * xr1[g].y;
      A1.z += c * xr1[g].z; A1.w += c * xr1[g].w;
    }
    uint4 o;
    o.x = (unsigned)f2bf(A0.x) | ((unsigned)f2bf(A0.y) << 16);
    o.y = (unsigned)f2bf(A0.z) | ((unsigned)f2bf(A0.w) << 16);
    o.z = (unsigned)f2bf(A1.x) | ((unsigned)f2bf(A1.y) << 16);
    o.w = (unsigned)f2bf(A1.z) | ((unsigned)f2bf(A1.w) << 16);
    *reinterpret_cast<uint4*>(orow + cumK(i) + j * 512 + u * 8) = o;
  }
}

// ---------------------------------------------------------------------------
// Kernel 2: cast-copy W_i (fp32, row-major [1024, K_i]) into concatenated
// bf16 Wcat (region base = cumK(i)*1024 elements). Layouts are identical
// within a region -> pure linear copy. 1024 elements per block; blocks per
// scale = K_i, cumulative block offset = cumK(i).
// ---------------------------------------------------------------------------
__global__ __launch_bounds__(256) void k_wcast(
    const float* W0, const float* W1, const float* W2, const float* W3,
    const float* W4, const float* W5, const float* W6,
    u16* __restrict__ Wcat) {
  int i = 0, rem = blockIdx.x;
  while (rem >= (8 - i) * 512) { rem -= (8 - i) * 512; ++i; }
  const float* Wi = (i == 0) ? W0 : (i == 1) ? W1 : (i == 2) ? W2 :
                    (i == 3) ? W3 : (i == 4) ? W4 : (i == 5) ? W5 : W6;
  const int t = threadIdx.x;
  const float4 w = reinterpret_cast<const float4*>(Wi)[(size_t)rem * 256 + t];
  ushort4 o;
  o.x = f2bf(w.x); o.y = f2bf(w.y); o.z = f2bf(w.z); o.w = f2bf(w.w);
  reinterpret_cast<ushort4*>(Wcat + ((size_t)cumK(i) + rem) * 1024)[t] = o;
}

// ---------------------------------------------------------------------------
// Kernel 3: multi-scale bf16 MFMA GEMM.
//   out[b, i*1024+d] = Xb[b, cumK(i):cumK(i)+K_i] . Wcat_i[d,:] + bias_i[d]
// 128x128 tile, BK=64 (32 KB LDS), 4 waves (2x2), 4x4 frags of 16x16x32.
// global_load_lds width-16 staging; 128-B LDS rows with slot (c+row)&7
// swizzle -> conflict-free (verified: SQ_LDS_BANK_CONFLICT == 0).
// Block->(scale,tile) map puts work {64,32,24,16} iters on 4-block CUs and
// {56,48,40} on 3-block CUs (b mod 256 ~ CU).
// ---------------------------------------------------------------------------
__device__ __forceinline__ void gl_lds16(const u16* g, u16* l) {
  __builtin_amdgcn_global_load_lds(
      (const __attribute__((address_space(1))) void*)g,
      (__attribute__((address_space(3))) void*)l, 16, 0, 0);
}

__global__ __launch_bounds__(256) void k_gemm_ms(
    const u16* __restrict__ Xb, const u16* __restrict__ Wcat,
    const float* b0, const float* b1, const float* b2, const float* b3,
    const float* b4, const float* b5, const float* b6,
    float* __restrict__ out) {
  __shared__ u16 sA[128 * 64];
  __shared__ u16 sB[128 * 64];
  const int r = blockIdx.x >> 7;
  const int i = (r == 0) ? 0 : (r == 1) ? 1 : (r == 2) ? 4 :
                (r == 3) ? 2 : (r == 4) ? 5 : (r == 5) ? 3 : 6;
  const int s = blockIdx.x & 127;
  const int m0 = (s >> 3) * 128;
  const int n0loc = (s & 7) * 128;
  const int K = (8 - i) * 512;
  const int niter = K >> 6;
  const size_t baseB = (size_t)cumK(i) * 1024;

  const int tid = threadIdx.x;
  const int lane = tid & 63;
  const int wave = tid >> 6;
  const int quad = lane >> 4;
  const int l15 = lane & 15;
  const int waveM = (wave >> 1) * 64;
  const int waveN = (wave & 1) * 64;

  // Staging: tile = 128 rows x 128 B = 1024 chunks of 16 B; 4 chunks/thread.
  const int srow = tid >> 3;          // 0..31
  const int sslot = tid & 7;
  const int gch = (sslot - srow) & 7; // swizzle: global chunk for this slot
  const u16* pA0 = Xb + (size_t)(m0 + srow) * 17920 + cumK(i) + gch * 8;
  const u16* pB0 = Wcat + baseB + (size_t)(n0loc + srow) * K + gch * 8;
  u16* lA0 = sA + tid * 8;
  u16* lB0 = sB + tid * 8;
  const size_t strideAj = (size_t)32 * 17920;
  const size_t strideBj = (size_t)32 * K;

  // LDS read offsets (u16 units): row*64 + (((t*4+quad)+row)&7)*8
  int offA[2][4], offB[2][4];
#pragma unroll
  for (int t = 0; t < 2; ++t) {
#pragma unroll
    for (int q = 0; q < 4; ++q) {
      int rowA = waveM + q * 16 + l15;
      offA[t][q] = rowA * 64 + (((t * 4 + quad) + rowA) & 7) * 8;
      int rowB = waveN + q * 16 + l15;
      offB[t][q] = rowB * 64 + (((t * 4 + quad) + rowB) & 7) * 8;
    }
  }

  f32x4 acc[4][4];
#pragma unroll
  for (int q = 0; q < 4; ++q)
#pragma unroll
    for (int c = 0; c < 4; ++c) {
      f32x4 z = {0.f, 0.f, 0.f, 0.f};
      acc[q][c] = z;
    }

  for (int kt = 0; kt < niter; ++kt) {
    const size_t ko = (size_t)kt * 64;
#pragma unroll
    for (int j = 0; j < 4; ++j) {
      gl_lds16(pA0 + j * strideAj + ko, lA0 + j * 2048);
      gl_lds16(pB0 + j * strideBj + ko, lB0 + j * 2048);
    }
    __syncthreads();

#pragma unroll
    for (int t = 0; t < 2; ++t) {
      bf16x8 av[4], bv[4];
#pragma unroll
      for (int q = 0; q < 4; ++q) av[q] = *reinterpret_cast<const bf16x8*>(sA + offA[t][q]);
#pragma unroll
      for (int c = 0; c < 4; ++c) bv[c] = *reinterpret_cast<const bf16x8*>(sB + offB[t][c]);
#pragma unroll
      for (int q = 0; q < 4; ++q)
#pragma unroll
        for (int c = 0; c < 4; ++c)
          acc[q][c] = __builtin_amdgcn_mfma_f32_16x16x32_bf16(av[q], bv[c], acc[q][c], 0, 0, 0);
    }
    __syncthreads();
  }

  const float* bi = (i == 0) ? b0 : (i == 1) ? b1 : (i == 2) ? b2 :
                    (i == 3) ? b3 : (i == 4) ? b4 : (i == 5) ? b5 : b6;
  // Epilogue: C/D layout row = quad*4 + reg, col = lane&15
#pragma unroll
  for (int c = 0; c < 4; ++c) {
    const int nloc = n0loc + waveN + c * 16 + l15;
    const float bias = bi[nloc];
    const int ncol = i * 1024 + nloc;
#pragma unroll
    for (int q = 0; q < 4; ++q) {
      const int mbase = m0 + waveM + q * 16 + quad * 4;
#pragma unroll
      for (int reg = 0; reg < 4; ++reg)
        out[(size_t)(mbase + reg) * 7168 + ncol] = acc[q][c][reg] + bias;
    }
  }
}

// ---------------------------------------------------------------------------
extern "C" void kernel_launch(void* const* d_in, const int* in_sizes, int n_in,
                              void* d_out, int out_size, void* d_ws, size_t ws_size,
                              hipStream_t stream) {
  const float* input = (const float*)d_in[0];
  const int* perms[7];
  const float* W[7];
  const float* bias[7];
  for (int i = 0; i < 7; ++i) {
    perms[i] = (const int*)d_in[1 + 3 * i];
    W[i]     = (const float*)d_in[2 + 3 * i];
    bias[i]  = (const float*)d_in[3 + 3 * i];
  }
  char* ws = (char*)d_ws;
  u16* Xb   = (u16*)ws;                          // 2048*17920 bf16 = 73.4 MB
  u16* Wcat = (u16*)(ws + (size_t)2048 * 17920 * 2);  // 18.35M bf16 = 36.7 MB

  k_xbar<<<2048, 256, 0, stream>>>(input, perms[0], perms[1], perms[2], perms[3],
                                   perms[4], perms[5], perms[6], Xb);
  k_wcast<<<17920, 256, 0, stream>>>(W[0], W[1], W[2], W[3], W[4], W[5], W[6], Wcat);
  k_gemm_ms<<<896, 256, 0, stream>>>(Xb, Wcat,
                                     bias[0], bias[1], bias[2], bias[3],
                                     bias[4], bias[5], bias[6],
                                     (float*)d_out);
}

// Round 4
// 278.993 us; speedup vs baseline: 1.4235x; 1.1523x over previous
//
#include <hip/hip_runtime.h>

typedef unsigned short u16;
typedef __bf16 bf16x8 __attribute__((ext_vector_type(8)));
typedef float f32x4 __attribute__((ext_vector_type(4)));

// fp32 -> bf16 round-to-nearest-even (finite, small values; no NaN path)
__device__ __forceinline__ u16 f2bf(float f) {
  unsigned int u = __float_as_uint(f);
  return (u16)((u + 0x7fffu + ((u >> 16) & 1u)) >> 16);
}

// cumK(i) = sum_{i'<i} (8-i')*512 = 256*i*(17-i); K_i = (8-i)*512
__device__ __forceinline__ int cumK(int i) { return 256 * i * (17 - i); }

// ---------------------------------------------------------------------------
// Kernel 1: xbar build. For each batch row b:
//   Xb[b, cumK(i) + j*512 + f] = bf16( sum_g C_i[g,j] * x[b, g*512 + f] )
// ---------------------------------------------------------------------------
__global__ __launch_bounds__(256) void k_xbar(
    const float* __restrict__ x,
    const int* p0, const int* p1, const int* p2, const int* p3,
    const int* p4, const int* p5, const int* p6,
    u16* __restrict__ Xb) {
  __shared__ float sc[448];
  const int b = blockIdx.x;
  const int t = threadIdx.x;
  const int* ps[7] = {p0, p1, p2, p3, p4, p5, p6};
  for (int cell = t; cell < 448; cell += 256) {
    int i = cell >> 6, rem = cell & 63, g = rem >> 3, j = rem & 7;
    int scale = 8 - i;
    float v = 0.f;
    if (j < scale) {
      const int* p = ps[i];
      int cnt = 0;
      for (int s = 0; s < 12; ++s) cnt += (p[s * scale + j] == g) ? 1 : 0;
      v = (float)cnt * (1.0f / 12.0f);
    }
    sc[cell] = v;
  }
  __syncthreads();
  const int u = t & 63;
  const int wv = t >> 6;
  const float4* xrow = reinterpret_cast<const float4*>(x + (size_t)b * 4096);
  float4 xr0[8], xr1[8];
#pragma unroll
  for (int g = 0; g < 8; ++g) {
    xr0[g] = xrow[g * 128 + u * 2];
    xr1[g] = xrow[g * 128 + u * 2 + 1];
  }
  u16* orow = Xb + (size_t)b * 17920;
  for (int s = wv; s < 35; s += 4) {
    int i = 0, rem = s;                 // wave-uniform decode of (i, j)
    while (rem >= 8 - i) { rem -= 8 - i; ++i; }
    const int j = rem;
    float4 A0 = make_float4(0.f, 0.f, 0.f, 0.f);
    float4 A1 = make_float4(0.f, 0.f, 0.f, 0.f);
#pragma unroll
    for (int g = 0; g < 8; ++g) {
      const float c = sc[i * 64 + g * 8 + j];
      A0.x += c * xr0[g].x; A0.y += c * xr0[g].y;
      A0.z += c * xr0[g].z; A0.w += c * xr0[g].w;
      A1.x += c * xr1[g].x; A1.y += c * xr1[g].y;
      A1.z += c * xr1[g].z; A1.w += c * xr1[g].w;
    }
    uint4 o;
    o.x = (unsigned)f2bf(A0.x) | ((unsigned)f2bf(A0.y) << 16);
    o.y = (unsigned)f2bf(A0.z) | ((unsigned)f2bf(A0.w) << 16);
    o.z = (unsigned)f2bf(A1.x) | ((unsigned)f2bf(A1.y) << 16);
    o.w = (unsigned)f2bf(A1.z) | ((unsigned)f2bf(A1.w) << 16);
    *reinterpret_cast<uint4*>(orow + cumK(i) + j * 512 + u * 8) = o;
  }
}

// ---------------------------------------------------------------------------
// Kernel 2: cast-copy W_i fp32 -> concatenated bf16 Wcat (linear copy).
// ---------------------------------------------------------------------------
__global__ __launch_bounds__(256) void k_wcast(
    const float* W0, const float* W1, const float* W2, const float* W3,
    const float* W4, const float* W5, const float* W6,
    u16* __restrict__ Wcat) {
  int i = 0, rem = blockIdx.x;
  while (rem >= (8 - i) * 512) { rem -= (8 - i) * 512; ++i; }
  const float* Wi = (i == 0) ? W0 : (i == 1) ? W1 : (i == 2) ? W2 :
                    (i == 3) ? W3 : (i == 4) ? W4 : (i == 5) ? W5 : W6;
  const int t = threadIdx.x;
  const float4 w = reinterpret_cast<const float4*>(Wi)[(size_t)rem * 256 + t];
  ushort4 o;
  o.x = f2bf(w.x); o.y = f2bf(w.y); o.z = f2bf(w.z); o.w = f2bf(w.w);
  reinterpret_cast<ushort4*>(Wcat + ((size_t)cumK(i) + rem) * 1024)[t] = o;
}

// ---------------------------------------------------------------------------
// Kernel 3: multi-scale bf16 MFMA GEMM, 2-stage double-buffered pipeline.
//   out[b, i*1024+d] = Xb[b, cumK(i):+K_i] . Wcat_i[d,:] + bias_i[d]
// 128x128 tile, BK=64, dbuf LDS 2x32 KB. Per iter: issue next tile's 8
// global_load_lds, s_waitcnt vmcnt(8) (wait ONLY the previous tile — current
// loads stay in flight across the barrier), s_barrier, MFMA, s_barrier.
// Swizzled LDS (slot=(chunk+row)&7) -> conflict-free (verified 0 conflicts).
// XCD swizzle: blockIdx%8 = XCD owns a 4m x 4n region per scale.
// Scales ordered descending K so the 2nd occupancy phase is short blocks.
// ---------------------------------------------------------------------------
__device__ __forceinline__ void gl_lds16(const u16* g, u16* l) {
  __builtin_amdgcn_global_load_lds(
      (const __attribute__((address_space(1))) void*)g,
      (__attribute__((address_space(3))) void*)l, 16, 0, 0);
}

#define WAIT_VM8 0x0F78   // vmcnt=8, expcnt=7(nowait), lgkmcnt=15(nowait)
#define WAIT_VM0 0x0F70   // vmcnt=0, expcnt=7, lgkmcnt=15

__global__ __launch_bounds__(256) void k_gemm_ms(
    const u16* __restrict__ Xb, const u16* __restrict__ Wcat,
    const float* b0, const float* b1, const float* b2, const float* b3,
    const float* b4, const float* b5, const float* b6,
    float* __restrict__ out) {
  __shared__ u16 lds[2 * 16384];      // buf b: A at b*16384, B at b*16384+8192
  const int i = blockIdx.x >> 7;      // scale idx; iters 64,56,48,40,32,24,16
  const int s = blockIdx.x & 127;
  const int region = s & 7;           // -> XCD (blockIdx % 8)
  const int k = s >> 3;               // 0..15 within region
  const int mq = region >> 1;         // 0..3
  const int nq = region & 1;          // 0..1
  const int m0 = (mq * 4 + (k & 3)) * 128;
  const int n0loc = (nq * 4 + (k >> 2)) * 128;
  const int K = (8 - i) * 512;
  const int niter = K >> 6;
  const size_t baseB = (size_t)cumK(i) * 1024;

  const int tid = threadIdx.x;
  const int lane = tid & 63;
  const int wave = tid >> 6;
  const int quad = lane >> 4;
  const int l15 = lane & 15;
  const int waveM = (wave >> 1) * 64;
  const int waveN = (wave & 1) * 64;

  // Staging: tile = 128 rows x 128 B = 1024 chunks of 16 B; 4 chunks/thread
  // per matrix. Swizzle: chunk for slot sslot of row srow is (sslot-srow)&7.
  const int srow = tid >> 3;          // 0..31
  const int sslot = tid & 7;
  const int gch = (sslot - srow) & 7;
  const u16* pA0 = Xb + (size_t)(m0 + srow) * 17920 + cumK(i) + gch * 8;
  const u16* pB0 = Wcat + baseB + (size_t)(n0loc + srow) * K + gch * 8;
  const size_t strideAj = (size_t)32 * 17920;
  const size_t strideBj = (size_t)32 * K;
  u16* lA0 = lds + tid * 8;
  u16* lB0 = lds + 8192 + tid * 8;

  // LDS read offsets (u16 units, buffer 0): row*64 + (((t*4+quad)+row)&7)*8
  int offA[2][4], offB[2][4];
#pragma unroll
  for (int t = 0; t < 2; ++t) {
#pragma unroll
    for (int q = 0; q < 4; ++q) {
      int rowA = waveM + q * 16 + l15;
      offA[t][q] = rowA * 64 + (((t * 4 + quad) + rowA) & 7) * 8;
      int rowB = waveN + q * 16 + l15;
      offB[t][q] = 8192 + rowB * 64 + (((t * 4 + quad) + rowB) & 7) * 8;
    }
  }

  f32x4 acc[4][4];
#pragma unroll
  for (int q = 0; q < 4; ++q)
#pragma unroll
    for (int c = 0; c < 4; ++c) {
      f32x4 z = {0.f, 0.f, 0.f, 0.f};
      acc[q][c] = z;
    }

  // Prologue: tile 0 -> buffer 0
#pragma unroll
  for (int j = 0; j < 4; ++j) {
    gl_lds16(pA0 + j * strideAj, lA0 + j * 2048);
    gl_lds16(pB0 + j * strideBj, lB0 + j * 2048);
  }

  for (int kt = 0; kt < niter - 1; ++kt) {
    // Issue next tile into the other buffer (stays in flight past barrier)
    const size_t ko = (size_t)(kt + 1) * 64;
    const int nb = ((kt + 1) & 1) << 14;
#pragma unroll
    for (int j = 0; j < 4; ++j) {
      gl_lds16(pA0 + j * strideAj + ko, lA0 + nb + j * 2048);
      gl_lds16(pB0 + j * strideBj + ko, lB0 + nb + j * 2048);
    }
    __builtin_amdgcn_s_waitcnt(WAIT_VM8);   // previous tile's 8 loads done
    __builtin_amdgcn_s_barrier();
    const int boff = (kt & 1) << 14;
#pragma unroll
    for (int t = 0; t < 2; ++t) {
      bf16x8 av[4], bv[4];
#pragma unroll
      for (int q = 0; q < 4; ++q) av[q] = *reinterpret_cast<const bf16x8*>(lds + boff + offA[t][q]);
#pragma unroll
      for (int c = 0; c < 4; ++c) bv[c] = *reinterpret_cast<const bf16x8*>(lds + boff + offB[t][c]);
#pragma unroll
      for (int q = 0; q < 4; ++q)
#pragma unroll
        for (int c = 0; c < 4; ++c)
          acc[q][c] = __builtin_amdgcn_mfma_f32_16x16x32_bf16(av[q], bv[c], acc[q][c], 0, 0, 0);
    }
    __builtin_amdgcn_s_barrier();   // all waves done reading buf before reuse
  }

  // Final tile
  __builtin_amdgcn_s_waitcnt(WAIT_VM0);
  __builtin_amdgcn_s_barrier();
  {
    const int boff = ((niter - 1) & 1) << 14;
#pragma unroll
    for (int t = 0; t < 2; ++t) {
      bf16x8 av[4], bv[4];
#pragma unroll
      for (int q = 0; q < 4; ++q) av[q] = *reinterpret_cast<const bf16x8*>(lds + boff + offA[t][q]);
#pragma unroll
      for (int c = 0; c < 4; ++c) bv[c] = *reinterpret_cast<const bf16x8*>(lds + boff + offB[t][c]);
#pragma unroll
      for (int q = 0; q < 4; ++q)
#pragma unroll
        for (int c = 0; c < 4; ++c)
          acc[q][c] = __builtin_amdgcn_mfma_f32_16x16x32_bf16(av[q], bv[c], acc[q][c], 0, 0, 0);
    }
  }

  const float* bi = (i == 0) ? b0 : (i == 1) ? b1 : (i == 2) ? b2 :
                    (i == 3) ? b3 : (i == 4) ? b4 : (i == 5) ? b5 : b6;
  // Epilogue: C/D layout row = quad*4 + reg, col = lane&15
#pragma unroll
  for (int c = 0; c < 4; ++c) {
    const int nloc = n0loc + waveN + c * 16 + l15;
    const float bias = bi[nloc];
    const int ncol = i * 1024 + nloc;
#pragma unroll
    for (int q = 0; q < 4; ++q) {
      const int mbase = m0 + waveM + q * 16 + quad * 4;
#pragma unroll
      for (int reg = 0; reg < 4; ++reg)
        out[(size_t)(mbase + reg) * 7168 + ncol] = acc[q][c][reg] + bias;
    }
  }
}

// ---------------------------------------------------------------------------
extern "C" void kernel_launch(void* const* d_in, const int* in_sizes, int n_in,
                              void* d_out, int out_size, void* d_ws, size_t ws_size,
                              hipStream_t stream) {
  const float* input = (const float*)d_in[0];
  const int* perms[7];
  const float* W[7];
  const float* bias[7];
  for (int i = 0; i < 7; ++i) {
    perms[i] = (const int*)d_in[1 + 3 * i];
    W[i]     = (const float*)d_in[2 + 3 * i];
    bias[i]  = (const float*)d_in[3 + 3 * i];
  }
  char* ws = (char*)d_ws;
  u16* Xb   = (u16*)ws;                               // 2048*17920 bf16 = 73.4 MB
  u16* Wcat = (u16*)(ws + (size_t)2048 * 17920 * 2);  // 18.35M bf16 = 36.7 MB

  k_xbar<<<2048, 256, 0, stream>>>(input, perms[0], perms[1], perms[2], perms[3],
                                   perms[4], perms[5], perms[6], Xb);
  k_wcast<<<17920, 256, 0, stream>>>(W[0], W[1], W[2], W[3], W[4], W[5], W[6], Wcat);
  k_gemm_ms<<<896, 256, 0, stream>>>(Xb, Wcat,
                                     bias[0], bias[1], bias[2], bias[3],
                                     bias[4], bias[5], bias[6],
                                     (float*)d_out);
}